// Round 2
// baseline (119.612 us; speedup 1.0000x reference)
//
#include <hip/hip_runtime.h>
#include <math.h>

#define B_  4
#define P_  512
#define K_  4
#define H_  200
#define W_  336
#define A_  14
#define PS_ 56
#define SCALE_ 0.25f
#define HWB_ (H_ * W_ * 4)         // bytes per (b,k) plane
#define NUNIT_ (PS_ * PS_ / 2)     // 1568 two-pixel units

__global__ __launch_bounds__(256) void blender_kernel(
    const float* __restrict__ bases,   // [B,K,H,W]
    const float* __restrict__ boxes,   // [B,P,4]
    const float* __restrict__ attn,    // [B,P,K,A,A]
    float* __restrict__ out)           // [B,P,PS,PS]
{
    const int tid = threadIdx.x;
    const int bp  = blockIdx.x;          // b*P_ + p
    const int b   = bp / P_;

    __shared__ float  smTile[K_ * A_ * A_];   // raw attn tile   (784 f)
    __shared__ float  smR[K_ * A_ * PS_];     // x-interp attn   (3136 f)
    __shared__ float4 smRX[PS_];              // {off_x0, off_dx, lx*vx, clx*vx}
    __shared__ float4 smRY[PS_];              // {off_y0, off_dy, ly*vy, cly*vy}
    __shared__ float2 smAY[PS_];              // {iy0*56 (elem off), ty}

    // ---- Phase 1a: stage attn tile ----
    const float* ap = attn + (size_t)bp * (K_ * A_ * A_);
    for (int i = tid; i < K_ * A_ * A_; i += 256) smTile[i] = ap[i];

    // ---- Phase 1b: separable tables ----
    const float* bx = boxes + (size_t)bp * 4;
    const float rr = (float)(A_ - 1) / (float)(PS_ - 1);  // 13/55

    if (tid < PS_) {                     // x-side
        const int px = tid;
        const float x1 = bx[0] * SCALE_;
        const float x2 = bx[2] * SCALE_;
        const float bw = fmaxf(x2 - x1, 1.0f) * (1.0f / PS_);
        const float sx = x1 + (px + 0.5f) * bw;
        const float vx = (sx > -1.0f && sx < (float)W_) ? 1.0f : 0.0f;
        const float cx = fminf(fmaxf(sx, 0.0f), (float)(W_ - 1));
        const int   x0 = (int)cx;
        const int   x1i = min(x0 + 1, W_ - 1);
        const float lx = cx - (float)x0;
        float4 v;
        v.x = __int_as_float(x0 * 4);
        v.y = __int_as_float((x1i - x0) * 4);
        v.z = lx * vx;
        v.w = (1.0f - lx) * vx;
        smRX[px] = v;
    } else if (tid >= 64 && tid < 64 + PS_) {   // y-side
        const int py = tid - 64;
        const float y1 = bx[1] * SCALE_;
        const float y2 = bx[3] * SCALE_;
        const float bh = fmaxf(y2 - y1, 1.0f) * (1.0f / PS_);
        const float sy = y1 + (py + 0.5f) * bh;
        const float vy = (sy > -1.0f && sy < (float)H_) ? 1.0f : 0.0f;
        const float cy = fminf(fmaxf(sy, 0.0f), (float)(H_ - 1));
        const int   y0 = (int)cy;
        const int   y1i = min(y0 + 1, H_ - 1);
        const float ly = cy - (float)y0;
        float4 v;
        v.x = __int_as_float(y0 * W_ * 4);
        v.y = __int_as_float((y1i - y0) * W_ * 4);
        v.z = ly * vy;
        v.w = (1.0f - ly) * vy;
        smRY[py] = v;
        const float srcy = (float)py * rr;
        int iy0 = min((int)srcy, A_ - 2);
        float2 a;
        a.x = __int_as_float(iy0 * PS_);
        a.y = srcy - (float)iy0;
        smAY[py] = a;
    }

    __syncthreads();

    // ---- Phase 2: x-interpolate attn -> R[k][A][PS] ----
    for (int i = tid; i < K_ * A_ * PS_; i += 256) {
        const int k  = i / (A_ * PS_);
        const int r1 = i - k * (A_ * PS_);
        const int ay = r1 / PS_;
        const int px = r1 - ay * PS_;
        const float srcx = (float)px * rr;
        int ix0 = min((int)srcx, A_ - 2);
        const float tx = srcx - (float)ix0;
        const float* t = smTile + k * (A_ * A_) + ay * A_ + ix0;
        smR[i] = t[0] * (1.0f - tx) + t[1] * tx;
    }

    __syncthreads();

    // ---- Phase 3: main loop, 2 px per unit ----
    const char* base_b = (const char*)(bases + (size_t)b * (K_ * H_ * W_));
    float* outp = out + (size_t)bp * (PS_ * PS_);

    for (int u = tid; u < NUNIT_; u += 256) {
        const int py  = u / (PS_ / 2);
        const int px0 = (u - py * (PS_ / 2)) * 2;

        const float4 ry = smRY[py];
        const int yoff = __float_as_int(ry.x);
        const int dy   = __float_as_int(ry.y);
        const float ly = ry.z, cly = ry.w;
        const float2 ayv = smAY[py];
        const int ayoff = __float_as_int(ayv.x);
        const float ty = ayv.y, cty = 1.0f - ty;

        float res[2];
        #pragma unroll
        for (int j = 0; j < 2; ++j) {
            const int px = px0 + j;
            const float4 rx = smRX[px];
            const int xoff = __float_as_int(rx.x);
            const int dx   = __float_as_int(rx.y);
            const float lx = rx.z, clx = rx.w;

            const float w00 = cly * clx, w01 = cly * lx;
            const float w10 = ly * clx,  w11 = ly * lx;

            const int o00 = yoff + xoff;
            const int o01 = o00 + dx;
            const int o10 = o00 + dy;
            const int o11 = o01 + dy;

            const float* rbase = smR + ayoff + px;   // + k*784 / +56 via imm offsets

            float s = 0.0f, acc = 0.0f;
            #pragma unroll
            for (int k = 0; k < K_; ++k) {
                const char* fb = base_b + k * HWB_;
                const float v = *(const float*)(fb + o00) * w00
                              + *(const float*)(fb + o01) * w01
                              + *(const float*)(fb + o10) * w10
                              + *(const float*)(fb + o11) * w11;
                const float a0 = rbase[k * (A_ * PS_)];
                const float a1 = rbase[k * (A_ * PS_) + PS_];
                const float a  = a0 * cty + a1 * ty;
                const float e  = __expf(a);     // no max-sub: |a| small
                s   += e;
                acc += e * v;
            }
            res[j] = acc * __builtin_amdgcn_rcpf(s);
        }
        float2 st; st.x = res[0]; st.y = res[1];
        *(float2*)(outp + py * PS_ + px0) = st;
    }
}

extern "C" void kernel_launch(void* const* d_in, const int* in_sizes, int n_in,
                              void* d_out, int out_size, void* d_ws, size_t ws_size,
                              hipStream_t stream) {
    const float* bases = (const float*)d_in[0];  // [B,K,H,W]
    const float* boxes = (const float*)d_in[1];  // [B,P,4]
    const float* attn  = (const float*)d_in[2];  // [B,P,K,A,A]
    float* out = (float*)d_out;                  // [B,P,PS,PS]

    blender_kernel<<<dim3(B_ * P_), dim3(256), 0, stream>>>(bases, boxes, attn, out);
}

// Round 3
// 105.444 us; speedup vs baseline: 1.1344x; 1.1344x over previous
//
#include <hip/hip_runtime.h>
#include <math.h>

#define B_  4
#define P_  512
#define K_  4
#define H_  200
#define W_  336
#define A_  14
#define PS_ 56
#define SCALE_ 0.25f
#define HWB_ (H_ * W_ * 4)         // bytes per (b,k) feature plane

#if __has_builtin(__builtin_amdgcn_exp2f)
#define EXP2F(x) __builtin_amdgcn_exp2f(x)
#else
#define EXP2F(x) exp2f(x)
#endif

__global__ __launch_bounds__(256) void blender_kernel(
    const float* __restrict__ bases,   // [B,K,H,W]
    const float* __restrict__ boxes,   // [B,P,4]
    const float* __restrict__ attn,    // [B,P,K,A,A]
    float* __restrict__ out)           // [B,P,PS,PS]
{
    const int tid = threadIdx.x;
    const int bp  = blockIdx.x;          // b*P_ + p
    const int b   = bp >> 9;             // / 512

    __shared__ float smTile[K_ * A_ * A_];    // raw attn tile (784 f)
    __shared__ float smR[K_ * A_ * PS_];      // x-interp attn * log2e (3136 f)
    // SoA tables (b32 reads, stride-1 lanes -> conflict-free)
    __shared__ int   smX0b[PS_], smDXb[PS_];
    __shared__ float smLX[PS_], smCLX[PS_];
    __shared__ int   smY0b[PS_], smDYb[PS_];
    __shared__ float smLY[PS_], smCLY[PS_];
    __shared__ int   smAYo[PS_];
    __shared__ float smTY[PS_];

    // ---- Phase 1a: stage attn tile ----
    const float* ap = attn + (size_t)bp * (K_ * A_ * A_);
    for (int i = tid; i < K_ * A_ * A_; i += 256) smTile[i] = ap[i];

    // ---- Phase 1b: separable tables ----
    const float* bx = boxes + (size_t)bp * 4;
    const float rr = 13.0f / 55.0f;          // (A-1)/(PS-1)

    if (tid < PS_) {                          // x-side
        const int px = tid;
        const float x1 = bx[0] * SCALE_;
        const float x2 = bx[2] * SCALE_;
        const float bw = fmaxf(x2 - x1, 1.0f) * (1.0f / PS_);
        const float sx = x1 + (px + 0.5f) * bw;
        const float vx = (sx > -1.0f && sx < (float)W_) ? 1.0f : 0.0f;
        const float cx = fminf(fmaxf(sx, 0.0f), (float)(W_ - 1));
        const int   x0 = (int)cx;
        const int   x1i = min(x0 + 1, W_ - 1);
        const float lx = cx - (float)x0;
        smX0b[px] = x0 * 4;
        smDXb[px] = (x1i - x0) * 4;
        smLX[px]  = lx * vx;
        smCLX[px] = (1.0f - lx) * vx;
    } else if (tid >= 64 && tid < 64 + PS_) { // y-side
        const int py = tid - 64;
        const float y1 = bx[1] * SCALE_;
        const float y2 = bx[3] * SCALE_;
        const float bh = fmaxf(y2 - y1, 1.0f) * (1.0f / PS_);
        const float sy = y1 + (py + 0.5f) * bh;
        const float vy = (sy > -1.0f && sy < (float)H_) ? 1.0f : 0.0f;
        const float cy = fminf(fmaxf(sy, 0.0f), (float)(H_ - 1));
        const int   y0 = (int)cy;
        const int   y1i = min(y0 + 1, H_ - 1);
        const float ly = cy - (float)y0;
        smY0b[py] = y0 * (W_ * 4);
        smDYb[py] = (y1i - y0) * (W_ * 4);
        smLY[py]  = ly * vy;
        smCLY[py] = (1.0f - ly) * vy;
        const float srcy = (float)py * rr;
        const int iy0 = min((int)srcy, A_ - 2);
        smAYo[py] = iy0 * PS_;
        smTY[py]  = srcy - (float)iy0;
    }
    __syncthreads();

    // ---- Phase 2: x-interp attn -> smR[k][A][PS], pre-scaled by log2(e) ----
    const float LOG2E = 1.4426950408889634f;
    for (int i = tid; i < K_ * A_ * PS_; i += 256) {
        const int k  = i / (A_ * PS_);
        const int r1 = i - k * (A_ * PS_);
        const int ay = r1 / PS_;
        const int px = r1 - ay * PS_;
        const float srcx = (float)px * rr;
        const int ix0 = min((int)srcx, A_ - 2);
        const float tx = srcx - (float)ix0;
        const float* t = smTile + k * (A_ * A_) + ay * A_ + ix0;
        smR[i] = (t[0] + tx * (t[1] - t[0])) * LOG2E;
    }
    __syncthreads();

    // ---- Phase 3: lane<->px stride-1, 2 independent px per iteration ----
    const char* fb = (const char*)(bases + (size_t)b * (K_ * H_ * W_));
    float* outp = out + (size_t)bp * (PS_ * PS_);

    auto pixel = [&](int idx) -> float {
        const int py = idx / PS_;
        const int px = idx - py * PS_;
        const int o00 = smY0b[py] + smX0b[px];
        const int dx  = smDXb[px];
        const int dy  = smDYb[py];
        const float lx = smLX[px], clx = smCLX[px];
        const float ly = smLY[py], cly = smCLY[py];
        const float w00 = cly * clx, w01 = cly * lx;
        const float w10 = ly * clx,  w11 = ly * lx;
        const int o01 = o00 + dx;
        const int o10 = o00 + dy;
        const int o11 = o10 + dx;
        const float* rb = smR + smAYo[py] + px;
        const float ty = smTY[py];

        float s = 0.0f, acc = 0.0f;
        #pragma unroll
        for (int k = 0; k < K_; ++k) {
            const char* f = fb + k * HWB_;      // uniform SGPR base per k
            const float v = *(const float*)(f + o00) * w00
                          + *(const float*)(f + o01) * w01
                          + *(const float*)(f + o10) * w10
                          + *(const float*)(f + o11) * w11;
            const float a0 = rb[k * (A_ * PS_)];
            const float a1 = rb[k * (A_ * PS_) + PS_];
            const float a  = a0 + ty * (a1 - a0);
            const float e  = EXP2F(a);          // smR pre-scaled by log2e
            s   += e;
            acc  = fmaf(e, v, acc);
        }
        return acc * __builtin_amdgcn_rcpf(s);
    };

    // 3136 = 6*512 + 64: six 2-px iterations + one 64-px tail
    int idx = tid;
    #pragma unroll 1
    for (int it = 0; it < 6; ++it, idx += 512) {
        const float r0 = pixel(idx);
        const float r1 = pixel(idx + 256);
        outp[idx]       = r0;
        outp[idx + 256] = r1;
    }
    if (tid < 64) {
        const int t = 3072 + tid;
        outp[t] = pixel(t);
    }
}

extern "C" void kernel_launch(void* const* d_in, const int* in_sizes, int n_in,
                              void* d_out, int out_size, void* d_ws, size_t ws_size,
                              hipStream_t stream) {
    const float* bases = (const float*)d_in[0];  // [B,K,H,W]
    const float* boxes = (const float*)d_in[1];  // [B,P,4]
    const float* attn  = (const float*)d_in[2];  // [B,P,K,A,A]
    float* out = (float*)d_out;                  // [B,P,PS,PS]

    blender_kernel<<<dim3(B_ * P_), dim3(256), 0, stream>>>(bases, boxes, attn, out);
}

// Round 4
// 105.234 us; speedup vs baseline: 1.1366x; 1.0020x over previous
//
#include <hip/hip_runtime.h>
#include <math.h>

#define B_  4
#define P_  512
#define K_  4
#define H_  200
#define W_  336
#define A_  14
#define PS_ 56
#define SCALE_ 0.25f
#define HWB_ (H_ * W_ * 4)     // bytes per (b,k) feature plane
#define APS_ (A_ * PS_)

#if __has_builtin(__builtin_amdgcn_exp2f)
#define EXP2F(x) __builtin_amdgcn_exp2f(x)
#else
#define EXP2F(x) exp2f(x)
#endif

__global__ __launch_bounds__(256) void blender_kernel(
    const float* __restrict__ bases,   // [B,K,H,W]
    const float* __restrict__ boxes,   // [B,P,4]
    const float* __restrict__ attn,    // [B,P,K,A,A]
    float* __restrict__ out)           // [B,P,PS,PS]
{
    const int tid = threadIdx.x;
    const int bp  = blockIdx.x;          // b*P_ + p
    const int b   = bp >> 9;             // / 512

    __shared__ float  smTile[K_ * A_ * A_];   // raw attn tile (784 f)
    __shared__ float  smR[K_ * APS_];         // x-interp attn * log2e (3136 f)
    __shared__ float4 smX[PS_];               // {asint(x0*4), asint(dx*4), lx*vx, clx*vx}
    __shared__ float4 smY[PS_];               // {asint(y0*W*4), asint(dy*W*4), ly*vy, cly*vy}
    __shared__ float2 smAY[PS_];              // {asint(iy0*56), ty}

    // ---- Phase 1a: stage attn tile (read-once -> nontemporal) ----
    const float* ap = attn + (size_t)bp * (K_ * A_ * A_);
    for (int i = tid; i < K_ * A_ * A_; i += 256)
        smTile[i] = __builtin_nontemporal_load(ap + i);

    // ---- Phase 1b: separable tables ----
    const float* bx = boxes + (size_t)bp * 4;
    const float rr = 13.0f / 55.0f;          // (A-1)/(PS-1)

    if (tid < PS_) {                          // x-side
        const int px = tid;
        const float x1 = bx[0] * SCALE_;
        const float x2 = bx[2] * SCALE_;
        const float bw = fmaxf(x2 - x1, 1.0f) * (1.0f / PS_);
        const float sx = x1 + (px + 0.5f) * bw;
        const float vx = (sx > -1.0f && sx < (float)W_) ? 1.0f : 0.0f;
        const float cx = fminf(fmaxf(sx, 0.0f), (float)(W_ - 1));
        const int   x0 = (int)cx;
        const int   x1i = min(x0 + 1, W_ - 1);
        const float lx = cx - (float)x0;
        float4 v;
        v.x = __int_as_float(x0 * 4);
        v.y = __int_as_float((x1i - x0) * 4);
        v.z = lx * vx;
        v.w = (1.0f - lx) * vx;
        smX[px] = v;
    } else if (tid >= 64 && tid < 64 + PS_) { // y-side
        const int py = tid - 64;
        const float y1 = bx[1] * SCALE_;
        const float y2 = bx[3] * SCALE_;
        const float bh = fmaxf(y2 - y1, 1.0f) * (1.0f / PS_);
        const float sy = y1 + (py + 0.5f) * bh;
        const float vy = (sy > -1.0f && sy < (float)H_) ? 1.0f : 0.0f;
        const float cy = fminf(fmaxf(sy, 0.0f), (float)(H_ - 1));
        const int   y0 = (int)cy;
        const int   y1i = min(y0 + 1, H_ - 1);
        const float ly = cy - (float)y0;
        float4 v;
        v.x = __int_as_float(y0 * (W_ * 4));
        v.y = __int_as_float((y1i - y0) * (W_ * 4));
        v.z = ly * vy;
        v.w = (1.0f - ly) * vy;
        smY[py] = v;
        const float srcy = (float)py * rr;
        const int iy0 = min((int)srcy, A_ - 2);
        float2 a;
        a.x = __int_as_float(iy0 * PS_);
        a.y = srcy - (float)iy0;
        smAY[py] = a;
    }
    __syncthreads();

    // ---- Phase 2: x-interp attn -> smR[k][A][PS], pre-scaled by log2(e) ----
    const float LOG2E = 1.4426950408889634f;
    for (int i = tid; i < K_ * APS_; i += 256) {
        const int k  = i / APS_;
        const int r1 = i - k * APS_;
        const int ay = r1 / PS_;
        const int px = r1 - ay * PS_;
        const float srcx = (float)px * rr;
        const int ix0 = min((int)srcx, A_ - 2);
        const float tx = srcx - (float)ix0;
        const float* t = smTile + k * (A_ * A_) + ay * A_ + ix0;
        smR[i] = (t[0] + tx * (t[1] - t[0])) * LOG2E;
    }
    __syncthreads();

    // ---- Phase 3: 12 px/thread, 2-slot software pipeline + 64-px tail ----
    const char* fb = (const char*)(bases + (size_t)b * (K_ * H_ * W_));
    float* outp = out + (size_t)bp * (PS_ * PS_);

    auto prep = [&](int idx, int* o, float* w, const float*& rb, float& ty) {
        const int py = idx / PS_;
        const int px = idx - py * PS_;
        const float4 X = smX[px];          // ds_read_b128, conflict-free
        const float4 Y = smY[py];
        const float2 AY = smAY[py];
        const int o00 = __float_as_int(Y.x) + __float_as_int(X.x);
        const int dx  = __float_as_int(X.y);
        const int dy  = __float_as_int(Y.y);
        o[0] = o00;      o[1] = o00 + dx;
        o[2] = o00 + dy; o[3] = o00 + dy + dx;
        w[0] = Y.w * X.w; w[1] = Y.w * X.z;
        w[2] = Y.z * X.w; w[3] = Y.z * X.z;
        rb = smR + __float_as_int(AY.x) + px;
        ty = AY.y;
    };
    auto issue = [&](const int* o, float* g) {
        #pragma unroll
        for (int k = 0; k < K_; ++k) {
            const char* f = fb + k * HWB_;   // uniform base, per-lane byte offset
            #pragma unroll
            for (int c = 0; c < 4; ++c)
                g[k * 4 + c] = *(const float*)(f + o[c]);
        }
    };
    auto finish = [&](const float* g, const float* w, const float* rb, float ty) -> float {
        const float ct = 1.0f - ty;
        float s = 0.0f, acc = 0.0f;
        #pragma unroll
        for (int k = 0; k < K_; ++k) {
            const float v = g[k*4+0] * w[0] + g[k*4+1] * w[1]
                          + g[k*4+2] * w[2] + g[k*4+3] * w[3];
            const float a0 = rb[k * APS_];
            const float a1 = rb[k * APS_ + PS_];
            const float e  = EXP2F(a0 * ct + a1 * ty);   // smR pre-scaled by log2e
            s += e;
            acc = fmaf(e, v, acc);
        }
        return acc * __builtin_amdgcn_rcpf(s);
    };

    int   oA[4], oB[4];
    float wA[4], wB[4];
    float gA[16], gB[16];
    const float *rbA, *rbB;
    float tyA, tyB;

    // prologue: group 0 in slot A
    prep(tid, oA, wA, rbA, tyA);
    issue(oA, gA);

    #pragma unroll
    for (int g = 0; g < 12; g += 2) {
        // load group g+1 into B while computing group g from A
        prep(tid + (g + 1) * 256, oB, wB, rbB, tyB);
        issue(oB, gB);
        __builtin_nontemporal_store(finish(gA, wA, rbA, tyA), outp + tid + g * 256);

        // load group g+2 (or the 64-thread tail) into A while computing B
        if (g + 2 < 12) {
            prep(tid + (g + 2) * 256, oA, wA, rbA, tyA);
            issue(oA, gA);
        } else if (tid < 64) {
            prep(3072 + tid, oA, wA, rbA, tyA);
            issue(oA, gA);
        }
        __builtin_nontemporal_store(finish(gB, wB, rbB, tyB), outp + tid + (g + 1) * 256);
    }
    if (tid < 64)
        __builtin_nontemporal_store(finish(gA, wA, rbA, tyA), outp + 3072 + tid);
}

extern "C" void kernel_launch(void* const* d_in, const int* in_sizes, int n_in,
                              void* d_out, int out_size, void* d_ws, size_t ws_size,
                              hipStream_t stream) {
    const float* bases = (const float*)d_in[0];  // [B,K,H,W]
    const float* boxes = (const float*)d_in[1];  // [B,P,4]
    const float* attn  = (const float*)d_in[2];  // [B,P,K,A,A]
    float* out = (float*)d_out;                  // [B,P,PS,PS]

    blender_kernel<<<dim3(B_ * P_), dim3(256), 0, stream>>>(bases, boxes, attn, out);
}

// Round 5
// 96.698 us; speedup vs baseline: 1.2370x; 1.0883x over previous
//
#include <hip/hip_runtime.h>
#include <math.h>

#define B_  4
#define P_  512
#define K_  4
#define H_  200
#define W_  336
#define A_  14
#define PS_ 56
#define SCALE_ 0.25f
#define HWB_ (H_ * W_ * 4)       // bytes per (b,k) feature plane
#define ROWB_ (W_ * 4)           // bytes per feature row
#define RROWB_ (PS_ * K_ * 4)    // bytes per smR row (= 896)

#if __has_builtin(__builtin_amdgcn_exp2f)
#define EXP2F(x) __builtin_amdgcn_exp2f(x)
#else
#define EXP2F(x) exp2f(x)
#endif

__global__ __launch_bounds__(448) void blender_kernel(
    const float* __restrict__ bases,   // [B,K,H,W]
    const float* __restrict__ boxes,   // [B,P,4]
    const float* __restrict__ attn,    // [B,P,K,A,A]
    float* __restrict__ out)           // [B,P,PS,PS]
{
    const int tid = threadIdx.x;       // 448 = 8*56 threads, 7 waves
    const int bp  = blockIdx.x;        // b*P_ + p
    const int b   = bp >> 9;           // / 512

    __shared__ float  smTile[K_ * A_ * A_];    // raw attn tile (784 f)
    __shared__ float  smR[A_ * PS_ * K_];      // x-interp attn*log2e, [ay][px][k] (12.25 KB)
    __shared__ float4 smX[PS_];                // {asint(xpair_byteoff), wl, wh, -}
    __shared__ float4 smY[PS_];                // {asint(y0_byteoff), asint(dy_byteoff), wy0, wy1}
    __shared__ float2 smAY[PS_];               // {asint(iy0*RROWB_), ty}

    // ---- Phase 1a: stage attn tile ----
    const float* ap = attn + (size_t)bp * (K_ * A_ * A_);
    for (int i = tid; i < K_ * A_ * A_; i += 448)
        smTile[i] = __builtin_nontemporal_load(ap + i);

    // ---- Phase 1b: separable tables ----
    const float* bx = boxes + (size_t)bp * 4;
    const float rr = 13.0f / 55.0f;            // (A-1)/(PS-1)

    if (tid < PS_) {                           // x-side: pair-load base + remapped weights
        const int px = tid;
        const float x1 = bx[0] * SCALE_;
        const float x2 = bx[2] * SCALE_;
        const float bw = fmaxf(x2 - x1, 1.0f) * (1.0f / PS_);
        const float sx = x1 + (px + 0.5f) * bw;
        const float vx = (sx > -1.0f && sx < (float)W_) ? 1.0f : 0.0f;
        const float cx = fminf(fmaxf(sx, 0.0f), (float)(W_ - 1));
        const int   x0 = (int)cx;
        const float lx = cx - (float)x0;
        float4 v;
        if (x0 >= W_ - 1) {                    // clamped: both samples = f[W-1]
            v.x = __int_as_float((W_ - 2) * 4);
            v.y = 0.0f;
            v.z = vx;                          // weight on element 1 (= x=W-1)
        } else {
            v.x = __int_as_float(x0 * 4);
            v.y = (1.0f - lx) * vx;            // element 0 weight
            v.z = lx * vx;                     // element 1 weight
        }
        v.w = 0.0f;
        smX[px] = v;
    } else if (tid >= 64 && tid < 64 + PS_) {  // y-side
        const int py = tid - 64;
        const float y1 = bx[1] * SCALE_;
        const float y2 = bx[3] * SCALE_;
        const float bh = fmaxf(y2 - y1, 1.0f) * (1.0f / PS_);
        const float sy = y1 + (py + 0.5f) * bh;
        const float vy = (sy > -1.0f && sy < (float)H_) ? 1.0f : 0.0f;
        const float cy = fminf(fmaxf(sy, 0.0f), (float)(H_ - 1));
        const int   y0 = (int)cy;
        const int   y1i = min(y0 + 1, H_ - 1);
        const float ly = cy - (float)y0;
        float4 v;
        v.x = __int_as_float(y0 * ROWB_);
        v.y = __int_as_float((y1i - y0) * ROWB_);
        v.z = (1.0f - ly) * vy;                // row0 weight
        v.w = ly * vy;                         // row1 weight
        smY[py] = v;
        const float srcy = (float)py * rr;
        const int iy0 = min((int)srcy, A_ - 2);
        float2 a;
        a.x = __int_as_float(iy0 * RROWB_);
        a.y = srcy - (float)iy0;
        smAY[py] = a;
    }
    __syncthreads();

    // ---- Phase 2: x-interp attn -> smR[ay][px][k], pre-scaled by log2(e) ----
    const float LOG2E = 1.4426950408889634f;
    for (int i = tid; i < K_ * A_ * PS_; i += 448) {   // 7 iters, i = k*784 + ay*56 + px
        const int k  = i / (A_ * PS_);
        const int r1 = i - k * (A_ * PS_);
        const int ay = r1 / PS_;
        const int px = r1 - ay * PS_;
        const float srcx = (float)px * rr;
        const int ix0 = min((int)srcx, A_ - 2);
        const float tx = srcx - (float)ix0;
        const float* t = smTile + k * (A_ * A_) + ay * A_ + ix0;
        smR[(ay * PS_ + px) * K_ + k] = (t[0] + tx * (t[1] - t[0])) * LOG2E;
    }
    __syncthreads();

    // ---- Phase 3: px fixed per thread; 7 rows per thread (py = py0 + 8t) ----
    const char* fb = (const char*)(bases + (size_t)b * (K_ * H_ * W_));
    float* outp = out + (size_t)bp * (PS_ * PS_);

    const int px  = tid % PS_;                 // 448 = 8*56 -> exact
    const int py0 = tid / PS_;                 // 0..7

    const float4 X = smX[px];                  // once per thread
    const unsigned xb = (unsigned)__float_as_int(X.x);
    const float wl = X.y, wh = X.z;
    const char* smRbase = (const char*)smR + (px << 4);   // + px*16B

    #pragma unroll
    for (int t = 0; t < 7; ++t) {
        const int py = py0 + 8 * t;
        const float4 Y  = smY[py];             // broadcast-ish (56 lanes same py)
        const float2 AY = smAY[py];
        const unsigned o0 = (unsigned)__float_as_int(Y.x) + xb;
        const unsigned o1 = o0 + (unsigned)__float_as_int(Y.y);
        const float wy0 = Y.z, wy1 = Y.w;
        const float ty  = AY.y;

        const float4 a0v = *(const float4*)(smRbase + __float_as_int(AY.x));
        const float4 a1v = *(const float4*)(smRbase + __float_as_int(AY.x) + RROWB_);

        float s = 0.0f, acc = 0.0f;
        #pragma unroll
        for (int k = 0; k < K_; ++k) {
            const char* f = fb + k * HWB_;     // uniform SGPR base per k
            const float2 r0 = *(const float2*)(f + o0);   // dwordx2 pair, row y0
            const float2 r1 = *(const float2*)(f + o1);   // dwordx2 pair, row y1
            const float rr0 = fmaf(r0.y, wh, r0.x * wl);
            const float rr1 = fmaf(r1.y, wh, r1.x * wl);
            const float v   = fmaf(rr1, wy1, rr0 * wy0);
            const float a0  = (k == 0) ? a0v.x : (k == 1) ? a0v.y : (k == 2) ? a0v.z : a0v.w;
            const float a1  = (k == 0) ? a1v.x : (k == 1) ? a1v.y : (k == 2) ? a1v.z : a1v.w;
            const float e   = EXP2F(fmaf(ty, a1 - a0, a0));  // pre-scaled by log2e
            s += e;
            acc = fmaf(e, v, acc);
        }
        __builtin_nontemporal_store(acc * __builtin_amdgcn_rcpf(s),
                                    outp + tid + 448 * t);
    }
}

extern "C" void kernel_launch(void* const* d_in, const int* in_sizes, int n_in,
                              void* d_out, int out_size, void* d_ws, size_t ws_size,
                              hipStream_t stream) {
    const float* bases = (const float*)d_in[0];  // [B,K,H,W]
    const float* boxes = (const float*)d_in[1];  // [B,P,4]
    const float* attn  = (const float*)d_in[2];  // [B,P,K,A,A]
    float* out = (float*)d_out;                  // [B,P,PS,PS]

    blender_kernel<<<dim3(B_ * P_), dim3(448), 0, stream>>>(bases, boxes, attn, out);
}

// Round 6
// 91.098 us; speedup vs baseline: 1.3130x; 1.0615x over previous
//
#include <hip/hip_runtime.h>
#include <math.h>

#define B_  4
#define P_  512
#define K_  4
#define H_  200
#define W_  336
#define A_  14
#define PS_ 56
#define SCALE_ 0.25f
#define HW_   (H_ * W_)
#define PLB_  (HW_ * 16)         // bytes per transposed (b) plane [H][W][K]
#define ROWB_ (W_ * 16)          // bytes per transposed feature row
#define RROWB_ (PS_ * K_ * 4)    // bytes per smR row (= 896)

#if __has_builtin(__builtin_amdgcn_exp2f)
#define EXP2F(x) __builtin_amdgcn_exp2f(x)
#else
#define EXP2F(x) exp2f(x)
#endif

// ---- Pass 1: bases [B,K,H,W] -> ws [B,H,W,K] (float4 per (b,y,x)) ----
__global__ __launch_bounds__(256) void transpose_bases(
    const float* __restrict__ bases, float4* __restrict__ ws)
{
    const int i = blockIdx.x * 256 + threadIdx.x;    // over B*H*W = 268800
    if (i >= B_ * HW_) return;
    const int b = i / HW_;
    const int r = i - b * HW_;                       // y*W + x
    const float* src = bases + (size_t)b * (K_ * HW_) + r;
    float4 v;
    v.x = src[0 * HW_];
    v.y = src[1 * HW_];
    v.z = src[2 * HW_];
    v.w = src[3 * HW_];
    ws[i] = v;
}

// ---- Pass 2: main blender ----
__global__ __launch_bounds__(448) void blender_kernel(
    const float4* __restrict__ wsb,    // [B,H,W,K] transposed bases
    const float* __restrict__ boxes,   // [B,P,4]
    const float* __restrict__ attn,    // [B,P,K,A,A]
    float* __restrict__ out)           // [B,P,PS,PS]
{
    const int tid = threadIdx.x;       // 448 = 8*56 threads, 7 waves
    const int bp  = blockIdx.x;        // b*P_ + p
    const int b   = bp >> 9;           // / 512

    __shared__ float  smTile[K_ * A_ * A_];    // raw attn tile (784 f)
    __shared__ float  smR[A_ * PS_ * K_];      // x-interp attn*log2e, [ay][px][k]
    __shared__ float4 smX[PS_];                // {asint(x0*16), wl, wh, -}
    __shared__ float4 smY[PS_];                // {asint(y0*ROWB), asint(dy*ROWB), wy0, wy1}
    __shared__ float2 smAY[PS_];               // {asint(iy0*RROWB_), ty}

    // ---- stage attn tile ----
    const float* ap = attn + (size_t)bp * (K_ * A_ * A_);
    for (int i = tid; i < K_ * A_ * A_; i += 448)
        smTile[i] = __builtin_nontemporal_load(ap + i);

    // ---- separable tables ----
    const float* bx = boxes + (size_t)bp * 4;
    const float rr = 13.0f / 55.0f;            // (A-1)/(PS-1)

    if (tid < PS_) {                           // x-side: pair base + remapped weights
        const int px = tid;
        const float x1 = bx[0] * SCALE_;
        const float x2 = bx[2] * SCALE_;
        const float bw = fmaxf(x2 - x1, 1.0f) * (1.0f / PS_);
        const float sx = x1 + (px + 0.5f) * bw;
        const float vx = (sx > -1.0f && sx < (float)W_) ? 1.0f : 0.0f;
        const float cx = fminf(fmaxf(sx, 0.0f), (float)(W_ - 1));
        const int   x0 = (int)cx;
        const float lx = cx - (float)x0;
        float4 v;
        if (x0 >= W_ - 1) {                    // clamped: both samples = f[W-1]
            v.x = __int_as_float((W_ - 2) * 16);
            v.y = 0.0f;
            v.z = vx;
        } else {
            v.x = __int_as_float(x0 * 16);
            v.y = (1.0f - lx) * vx;
            v.z = lx * vx;
        }
        v.w = 0.0f;
        smX[px] = v;
    } else if (tid >= 64 && tid < 64 + PS_) {  // y-side
        const int py = tid - 64;
        const float y1 = bx[1] * SCALE_;
        const float y2 = bx[3] * SCALE_;
        const float bh = fmaxf(y2 - y1, 1.0f) * (1.0f / PS_);
        const float sy = y1 + (py + 0.5f) * bh;
        const float vy = (sy > -1.0f && sy < (float)H_) ? 1.0f : 0.0f;
        const float cy = fminf(fmaxf(sy, 0.0f), (float)(H_ - 1));
        const int   y0 = (int)cy;
        const int   y1i = min(y0 + 1, H_ - 1);
        const float ly = cy - (float)y0;
        float4 v;
        v.x = __int_as_float(y0 * ROWB_);
        v.y = __int_as_float((y1i - y0) * ROWB_);
        v.z = (1.0f - ly) * vy;
        v.w = ly * vy;
        smY[py] = v;
        const float srcy = (float)py * rr;
        const int iy0 = min((int)srcy, A_ - 2);
        float2 a;
        a.x = __int_as_float(iy0 * RROWB_);
        a.y = srcy - (float)iy0;
        smAY[py] = a;
    }
    __syncthreads();

    // ---- x-interp attn -> smR[ay][px][k], pre-scaled by log2(e) ----
    const float LOG2E = 1.4426950408889634f;
    for (int i = tid; i < K_ * A_ * PS_; i += 448) {
        const int k  = i / (A_ * PS_);
        const int r1 = i - k * (A_ * PS_);
        const int ay = r1 / PS_;
        const int px = r1 - ay * PS_;
        const float srcx = (float)px * rr;
        const int ix0 = min((int)srcx, A_ - 2);
        const float tx = srcx - (float)ix0;
        const float* t = smTile + k * (A_ * A_) + ay * A_ + ix0;
        smR[(ay * PS_ + px) * K_ + k] = (t[0] + tx * (t[1] - t[0])) * LOG2E;
    }
    __syncthreads();

    // ---- main loop: px fixed per thread; 7 rows per thread ----
    const char* fb = (const char*)wsb + (size_t)b * PLB_;
    float* outp = out + (size_t)bp * (PS_ * PS_);

    const int px  = tid % PS_;
    const int py0 = tid / PS_;                 // 0..7

    const float4 X = smX[px];                  // once per thread
    const unsigned xb = (unsigned)__float_as_int(X.x);
    const float wl = X.y, wh = X.z;
    const char* smRbase = (const char*)smR + (px << 4);

    #pragma unroll
    for (int t = 0; t < 7; ++t) {
        const int py = py0 + 8 * t;
        const float4 Y  = smY[py];
        const float2 AY = smAY[py];
        const unsigned o0 = (unsigned)__float_as_int(Y.x) + xb;
        const unsigned o1 = o0 + (unsigned)__float_as_int(Y.y);
        const float wy0 = Y.z, wy1 = Y.w;
        const float ty  = AY.y;

        const float4 q00 = *(const float4*)(fb + o0);        // (y0,x0,  k0..3)
        const float4 q01 = *(const float4*)(fb + o0 + 16);   // (y0,x0+1,k0..3)
        const float4 q10 = *(const float4*)(fb + o1);        // (y1,x0,  k0..3)
        const float4 q11 = *(const float4*)(fb + o1 + 16);   // (y1,x0+1,k0..3)

        // x-lerp then y-lerp, 4-wide over k
        float vx0, vx1, vx2, vx3;
        {
            const float r0x = fmaf(q01.x, wh, q00.x * wl);
            const float r0y = fmaf(q01.y, wh, q00.y * wl);
            const float r0z = fmaf(q01.z, wh, q00.z * wl);
            const float r0w = fmaf(q01.w, wh, q00.w * wl);
            const float r1x = fmaf(q11.x, wh, q10.x * wl);
            const float r1y = fmaf(q11.y, wh, q10.y * wl);
            const float r1z = fmaf(q11.z, wh, q10.z * wl);
            const float r1w = fmaf(q11.w, wh, q10.w * wl);
            vx0 = fmaf(r1x, wy1, r0x * wy0);
            vx1 = fmaf(r1y, wy1, r0y * wy0);
            vx2 = fmaf(r1z, wy1, r0z * wy0);
            vx3 = fmaf(r1w, wy1, r0w * wy0);
        }

        const float4 a0v = *(const float4*)(smRbase + __float_as_int(AY.x));
        const float4 a1v = *(const float4*)(smRbase + __float_as_int(AY.x) + RROWB_);

        const float e0 = EXP2F(fmaf(ty, a1v.x - a0v.x, a0v.x));
        const float e1 = EXP2F(fmaf(ty, a1v.y - a0v.y, a0v.y));
        const float e2 = EXP2F(fmaf(ty, a1v.z - a0v.z, a0v.z));
        const float e3 = EXP2F(fmaf(ty, a1v.w - a0v.w, a0v.w));

        const float s   = (e0 + e1) + (e2 + e3);
        float acc = e0 * vx0;
        acc = fmaf(e1, vx1, acc);
        acc = fmaf(e2, vx2, acc);
        acc = fmaf(e3, vx3, acc);

        __builtin_nontemporal_store(acc * __builtin_amdgcn_rcpf(s),
                                    outp + tid + 448 * t);
    }
}

extern "C" void kernel_launch(void* const* d_in, const int* in_sizes, int n_in,
                              void* d_out, int out_size, void* d_ws, size_t ws_size,
                              hipStream_t stream) {
    const float* bases = (const float*)d_in[0];  // [B,K,H,W]
    const float* boxes = (const float*)d_in[1];  // [B,P,4]
    const float* attn  = (const float*)d_in[2];  // [B,P,K,A,A]
    float* out = (float*)d_out;                  // [B,P,PS,PS]
    float4* wsb = (float4*)d_ws;                 // 268800 * 16 B = 4.3 MB scratch

    transpose_bases<<<dim3((B_ * HW_ + 255) / 256), dim3(256), 0, stream>>>(bases, wsb);
    blender_kernel<<<dim3(B_ * P_), dim3(448), 0, stream>>>(wsb, boxes, attn, out);
}

// Round 7
// 90.285 us; speedup vs baseline: 1.3248x; 1.0090x over previous
//
#include <hip/hip_runtime.h>
#include <math.h>

#define B_  4
#define P_  512
#define K_  4
#define H_  200
#define W_  336
#define A_  14
#define PS_ 56
#define SCALE_ 0.25f
#define HW_    (H_ * W_)
#define PLB_   (HW_ * 16)        // bytes per transposed (b) plane [H][W] of uint4
#define ROWB_  (W_ * 16)         // bytes per transposed feature row (5376)
#define RROWB_ (PS_ * K_ * 4)    // bytes per smR row (= 896)

#if __has_builtin(__builtin_amdgcn_exp2f)
#define EXP2F(x) __builtin_amdgcn_exp2f(x)
#else
#define EXP2F(x) exp2f(x)
#endif

// bf16 round-to-nearest-even, manual (no API dependence)
static __device__ __forceinline__ unsigned f2bf(float x) {
    unsigned u = __float_as_uint(x);
    return (u + 0x7fffu + ((u >> 16) & 1u)) >> 16;
}
static __device__ __forceinline__ unsigned pk2(float a, float b) {
    return f2bf(a) | (f2bf(b) << 16);
}
#define LOF(u) __uint_as_float((u) << 16)
#define HIF(u) __uint_as_float((u) & 0xffff0000u)

// ---- Pass 1: bases [B,K,H,W] -> ws [B,H,W] uint4 = bf16 {x:(k0..3), x+1:(k0..3)} ----
__global__ __launch_bounds__(256) void transpose_bases(
    const float* __restrict__ bases, uint4* __restrict__ ws)
{
    const int i = blockIdx.x * 256 + threadIdx.x;    // over B*H*W = 268800
    if (i >= B_ * HW_) return;
    const int b = i / HW_;
    const int r = i - b * HW_;                       // y*W + x
    const int x = r % W_;
    const int dn = (x < W_ - 1) ? 1 : 0;             // x+1 clamped (duplicate at edge)
    const float* src = bases + (size_t)b * (K_ * HW_) + r;
    const float v0 = src[0 * HW_],      v1 = src[1 * HW_];
    const float v2 = src[2 * HW_],      v3 = src[3 * HW_];
    const float n0 = src[0 * HW_ + dn], n1 = src[1 * HW_ + dn];
    const float n2 = src[2 * HW_ + dn], n3 = src[3 * HW_ + dn];
    uint4 w;
    w.x = pk2(v0, v1); w.y = pk2(v2, v3);
    w.z = pk2(n0, n1); w.w = pk2(n2, n3);
    ws[i] = w;
}

// ---- Pass 2: main blender ----
__global__ __launch_bounds__(448) void blender_kernel(
    const uint4* __restrict__ wsb,     // [B,H,W] pair-duplicated bf16 bases
    const float* __restrict__ boxes,   // [B,P,4]
    const float* __restrict__ attn,    // [B,P,K,A,A]
    float* __restrict__ out)           // [B,P,PS,PS]
{
    const int tid = threadIdx.x;       // 448 = 8*56 threads, 7 waves
    const int bp  = blockIdx.x;        // b*P_ + p
    const int b   = bp >> 9;           // / 512

    __shared__ float  smTile[K_ * A_ * A_];    // raw attn tile (784 f)
    __shared__ float  smR[A_ * PS_ * K_];      // x-interp attn*log2e, [ay][px][k]
    __shared__ float4 smX[PS_];                // {asint(x0*16), wl, wh, -}
    __shared__ float4 smY[PS_];                // {asint(y0*ROWB), asint(dy*ROWB), wy0, wy1}
    __shared__ float2 smAY[PS_];               // {asint(iy0*RROWB_), ty}

    // ---- stage attn tile ----
    const float* ap = attn + (size_t)bp * (K_ * A_ * A_);
    for (int i = tid; i < K_ * A_ * A_; i += 448)
        smTile[i] = __builtin_nontemporal_load(ap + i);

    // ---- separable tables ----
    const float* bx = boxes + (size_t)bp * 4;
    const float rr = 13.0f / 55.0f;            // (A-1)/(PS-1)

    if (tid < PS_) {                           // x-side (no remap needed: pair layout)
        const int px = tid;
        const float x1 = bx[0] * SCALE_;
        const float x2 = bx[2] * SCALE_;
        const float bw = fmaxf(x2 - x1, 1.0f) * (1.0f / PS_);
        const float sx = x1 + (px + 0.5f) * bw;
        const float vx = (sx > -1.0f && sx < (float)W_) ? 1.0f : 0.0f;
        const float cx = fminf(fmaxf(sx, 0.0f), (float)(W_ - 1));
        const int   x0 = (int)cx;
        const float lx = cx - (float)x0;
        float4 v;
        v.x = __int_as_float(x0 * 16);
        v.y = (1.0f - lx) * vx;                // weight on element x0
        v.z = lx * vx;                         // weight on element x0+1
        v.w = 0.0f;
        smX[px] = v;
    } else if (tid >= 64 && tid < 64 + PS_) {  // y-side
        const int py = tid - 64;
        const float y1 = bx[1] * SCALE_;
        const float y2 = bx[3] * SCALE_;
        const float bh = fmaxf(y2 - y1, 1.0f) * (1.0f / PS_);
        const float sy = y1 + (py + 0.5f) * bh;
        const float vy = (sy > -1.0f && sy < (float)H_) ? 1.0f : 0.0f;
        const float cy = fminf(fmaxf(sy, 0.0f), (float)(H_ - 1));
        const int   y0 = (int)cy;
        const int   y1i = min(y0 + 1, H_ - 1);
        const float ly = cy - (float)y0;
        float4 v;
        v.x = __int_as_float(y0 * ROWB_);
        v.y = __int_as_float((y1i - y0) * ROWB_);
        v.z = (1.0f - ly) * vy;
        v.w = ly * vy;
        smY[py] = v;
        const float srcy = (float)py * rr;
        const int iy0 = min((int)srcy, A_ - 2);
        float2 a;
        a.x = __int_as_float(iy0 * RROWB_);
        a.y = srcy - (float)iy0;
        smAY[py] = a;
    }
    __syncthreads();

    // ---- x-interp attn -> smR[ay][px][k], pre-scaled by log2(e) ----
    const float LOG2E = 1.4426950408889634f;
    for (int i = tid; i < K_ * A_ * PS_; i += 448) {
        const int k  = i / (A_ * PS_);
        const int r1 = i - k * (A_ * PS_);
        const int ay = r1 / PS_;
        const int px = r1 - ay * PS_;
        const float srcx = (float)px * rr;
        const int ix0 = min((int)srcx, A_ - 2);
        const float tx = srcx - (float)ix0;
        const float* t = smTile + k * (A_ * A_) + ay * A_ + ix0;
        smR[(ay * PS_ + px) * K_ + k] = (t[0] + tx * (t[1] - t[0])) * LOG2E;
    }
    __syncthreads();

    // ---- main loop: px fixed per thread; 7 rows per thread; 2-slot pipeline ----
    const char* fb = (const char*)wsb + (size_t)b * PLB_;
    float* outp = out + (size_t)bp * (PS_ * PS_);

    const int px  = tid % PS_;
    const int py0 = tid / PS_;                 // 0..7

    const float4 X = smX[px];                  // once per thread
    const unsigned xb = (unsigned)__float_as_int(X.x);
    const float wl = X.y, wh = X.z;
    const char* smRbase = (const char*)smR + (px << 4);

    struct PState {
        uint4 r0, r1;
        float wy0, wy1, ty;
        int   ayo;
    };

    auto issue = [&](int t, PState& S) {
        const int py = py0 + 8 * t;
        const float4 Y  = smY[py];
        const float2 AY = smAY[py];
        const unsigned o0 = (unsigned)__float_as_int(Y.x) + xb;
        const unsigned o1 = o0 + (unsigned)__float_as_int(Y.y);
        S.r0 = *(const uint4*)(fb + o0);       // (y0, x0|x0+1, k0..3) bf16, 16B aligned
        S.r1 = *(const uint4*)(fb + o1);       // (y1, ...)
        S.wy0 = Y.z; S.wy1 = Y.w;
        S.ty = AY.y; S.ayo = __float_as_int(AY.x);
    };

    auto compute = [&](const PState& S) -> float {
        const float wy0 = S.wy0, wy1 = S.wy1, ty = S.ty;
        // unpack bf16 and bilinear-lerp, 4-wide over k
        const float r0a = fmaf(LOF(S.r0.z), wh, LOF(S.r0.x) * wl);
        const float r0b = fmaf(HIF(S.r0.z), wh, HIF(S.r0.x) * wl);
        const float r0c = fmaf(LOF(S.r0.w), wh, LOF(S.r0.y) * wl);
        const float r0d = fmaf(HIF(S.r0.w), wh, HIF(S.r0.y) * wl);
        const float r1a = fmaf(LOF(S.r1.z), wh, LOF(S.r1.x) * wl);
        const float r1b = fmaf(HIF(S.r1.z), wh, HIF(S.r1.x) * wl);
        const float r1c = fmaf(LOF(S.r1.w), wh, LOF(S.r1.y) * wl);
        const float r1d = fmaf(HIF(S.r1.w), wh, HIF(S.r1.y) * wl);
        const float v0 = fmaf(r1a, wy1, r0a * wy0);
        const float v1 = fmaf(r1b, wy1, r0b * wy0);
        const float v2 = fmaf(r1c, wy1, r0c * wy0);
        const float v3 = fmaf(r1d, wy1, r0d * wy0);

        const float4 a0v = *(const float4*)(smRbase + S.ayo);
        const float4 a1v = *(const float4*)(smRbase + S.ayo + RROWB_);
        const float e0 = EXP2F(fmaf(ty, a1v.x - a0v.x, a0v.x));
        const float e1 = EXP2F(fmaf(ty, a1v.y - a0v.y, a0v.y));
        const float e2 = EXP2F(fmaf(ty, a1v.z - a0v.z, a0v.z));
        const float e3 = EXP2F(fmaf(ty, a1v.w - a0v.w, a0v.w));

        const float s = (e0 + e1) + (e2 + e3);
        float acc = e0 * v0;
        acc = fmaf(e1, v1, acc);
        acc = fmaf(e2, v2, acc);
        acc = fmaf(e3, v3, acc);
        return acc * __builtin_amdgcn_rcpf(s);
    };

    PState SA, SB;
    issue(0, SA);
    #pragma unroll
    for (int g = 0; g < 6; g += 2) {
        issue(g + 1, SB);
        __builtin_nontemporal_store(compute(SA), outp + tid + 448 * g);
        issue(g + 2, SA);
        __builtin_nontemporal_store(compute(SB), outp + tid + 448 * (g + 1));
    }
    __builtin_nontemporal_store(compute(SA), outp + tid + 448 * 6);
}

extern "C" void kernel_launch(void* const* d_in, const int* in_sizes, int n_in,
                              void* d_out, int out_size, void* d_ws, size_t ws_size,
                              hipStream_t stream) {
    const float* bases = (const float*)d_in[0];  // [B,K,H,W]
    const float* boxes = (const float*)d_in[1];  // [B,P,4]
    const float* attn  = (const float*)d_in[2];  // [B,P,K,A,A]
    float* out = (float*)d_out;                  // [B,P,PS,PS]
    uint4* wsb = (uint4*)d_ws;                   // 268800 * 16 B = 4.3 MB scratch

    transpose_bases<<<dim3((B_ * HW_ + 255) / 256), dim3(256), 0, stream>>>(bases, wsb);
    blender_kernel<<<dim3(B_ * P_), dim3(448), 0, stream>>>(wsb, boxes, attn, out);
}